// Round 1
// baseline (3160.334 us; speedup 1.0000x reference)
//
#include <hip/hip_runtime.h>

#define TT 2048
#define BB 512
#define II 5
#define HH 64

__device__ __forceinline__ float sigm(float v)   { return 1.0f / (1.0f + __expf(-v)); }
__device__ __forceinline__ float tanh_f(float v) { return 1.0f - 2.0f / (1.0f + __expf(2.0f * v)); }

__global__ __launch_bounds__(256, 2) void lstm2_kernel(
    const float* __restrict__ x,
    const float* __restrict__ W_ih0, const float* __restrict__ W_hh0,
    const float* __restrict__ b_ih0, const float* __restrict__ b_hh0,
    const float* __restrict__ W_ih1, const float* __restrict__ W_hh1,
    const float* __restrict__ b_ih1, const float* __restrict__ b_hh1,
    const float* __restrict__ W_out, const float* __restrict__ b_out,
    float* __restrict__ out)
{
    const int t = threadIdx.x;      // gate row 0..255
    const int b = blockIdx.x;       // batch element
    const int gate = t >> 6;        // 0=i 1=f 2=g 3=o

    __shared__ __align__(16) float act[256];
    __shared__ __align__(16) float h1s[HH];
    __shared__ __align__(16) float h2s[HH];

    // ---- load this row's weights into registers (reused for all 2048 steps) ----
    float wih0[II];
    #pragma unroll
    for (int k = 0; k < II; ++k) wih0[k] = W_ih0[t * II + k];
    const float bias0 = b_ih0[t] + b_hh0[t];
    const float bias1 = b_ih1[t] + b_hh1[t];

    float4 whh0[16], wih1[16], whh1[16];
    const float4* p0 = (const float4*)(W_hh0 + t * HH);
    const float4* p1 = (const float4*)(W_ih1 + t * HH);
    const float4* p2 = (const float4*)(W_hh1 + t * HH);
    #pragma unroll
    for (int k = 0; k < 16; ++k) { whh0[k] = p0[k]; wih1[k] = p1[k]; whh1[k] = p2[k]; }

    float c1 = 0.0f, c2 = 0.0f;
    if (t < HH) { h1s[t] = 0.0f; h2s[t] = 0.0f; }
    __syncthreads();

    const float* xb = x + b * II;   // x[(step*BB + b)*II + k]
    float xc[II];
    #pragma unroll
    for (int k = 0; k < II; ++k) xc[k] = xb[k];

    for (int step = 0; step < TT; ++step) {
        // prefetch next step's x (wave-uniform scalar loads; hides HBM latency)
        float xn[II];
        if (step + 1 < TT) {
            const float* xnp = xb + (size_t)(step + 1) * (BB * II);
            #pragma unroll
            for (int k = 0; k < II; ++k) xn[k] = xnp[k];
        }

        // ---- layer 0: gate row t = bias + Wih0.x + Whh0.h1 ----
        float acc = bias0;
        #pragma unroll
        for (int k = 0; k < II; ++k) acc = fmaf(xc[k], wih0[k], acc);
        #pragma unroll
        for (int k = 0; k < 16; ++k) {
            float4 h = ((const float4*)h1s)[k];   // broadcast ds_read_b128
            acc = fmaf(h.x, whh0[k].x, acc);
            acc = fmaf(h.y, whh0[k].y, acc);
            acc = fmaf(h.z, whh0[k].z, acc);
            acc = fmaf(h.w, whh0[k].w, acc);
        }
        act[t] = (gate == 2) ? tanh_f(acc) : sigm(acc);
        __syncthreads();

        // ---- layer 0 state update (wave 0) ----
        if (t < HH) {
            float iv = act[t], fv = act[HH + t], gv = act[2 * HH + t], ov = act[3 * HH + t];
            c1 = fv * c1 + iv * gv;
            h1s[t] = ov * tanh_f(c1);
        }
        __syncthreads();

        // ---- layer 1: gate row t = bias + Wih1.h1_new + Whh1.h2_prev ----
        float acc2 = bias1;
        #pragma unroll
        for (int k = 0; k < 16; ++k) {
            float4 h = ((const float4*)h1s)[k];
            acc2 = fmaf(h.x, wih1[k].x, acc2);
            acc2 = fmaf(h.y, wih1[k].y, acc2);
            acc2 = fmaf(h.z, wih1[k].z, acc2);
            acc2 = fmaf(h.w, wih1[k].w, acc2);
        }
        #pragma unroll
        for (int k = 0; k < 16; ++k) {
            float4 h = ((const float4*)h2s)[k];
            acc2 = fmaf(h.x, whh1[k].x, acc2);
            acc2 = fmaf(h.y, whh1[k].y, acc2);
            acc2 = fmaf(h.z, whh1[k].z, acc2);
            acc2 = fmaf(h.w, whh1[k].w, acc2);
        }
        act[t] = (gate == 2) ? tanh_f(acc2) : sigm(acc2);
        __syncthreads();

        // ---- layer 1 state update (wave 0) ----
        if (t < HH) {
            float iv = act[t], fv = act[HH + t], gv = act[2 * HH + t], ov = act[3 * HH + t];
            c2 = fv * c2 + iv * gv;
            h2s[t] = ov * tanh_f(c2);
        }
        __syncthreads();

        #pragma unroll
        for (int k = 0; k < II; ++k) xc[k] = xn[k];
    }

    // ---- final projection: out[b] = h2 . W_out + b_out ----
    if (t < HH) {
        float v = h2s[t] * W_out[t];
        #pragma unroll
        for (int off = 32; off > 0; off >>= 1) v += __shfl_xor(v, off);
        if (t == 0) out[b] = v + b_out[0];
    }
}

extern "C" void kernel_launch(void* const* d_in, const int* in_sizes, int n_in,
                              void* d_out, int out_size, void* d_ws, size_t ws_size,
                              hipStream_t stream) {
    const float* x     = (const float*)d_in[0];
    const float* W_ih0 = (const float*)d_in[1];
    const float* W_hh0 = (const float*)d_in[2];
    const float* b_ih0 = (const float*)d_in[3];
    const float* b_hh0 = (const float*)d_in[4];
    const float* W_ih1 = (const float*)d_in[5];
    const float* W_hh1 = (const float*)d_in[6];
    const float* b_ih1 = (const float*)d_in[7];
    const float* b_hh1 = (const float*)d_in[8];
    const float* W_out = (const float*)d_in[9];
    const float* b_out = (const float*)d_in[10];
    float* out = (float*)d_out;

    lstm2_kernel<<<dim3(BB), dim3(256), 0, stream>>>(
        x, W_ih0, W_hh0, b_ih0, b_hh0, W_ih1, W_hh1, b_ih1, b_hh1, W_out, b_out, out);
}